// Round 5
// baseline (353.939 us; speedup 1.0000x reference)
//
#include <hip/hip_runtime.h>
#include <hip/hip_bf16.h>

#define B_ 4
#define T_ 2048
#define C_ 1024
#define H_ 16
#define D_ 64
#define SCALE_ 0.125f
#define L2E 1.4426950408889634f
#define SE (SCALE_ * L2E)

typedef __attribute__((ext_vector_type(8))) short bf16x8;
typedef __attribute__((ext_vector_type(4))) float f32x4;

__device__ __forceinline__ unsigned short f2bf(float f) {
    union { float f; unsigned u; } v; v.f = f;
    unsigned r = v.u + 0x7fff + ((v.u >> 16) & 1);
    return (unsigned short)(r >> 16);
}

__device__ __forceinline__ unsigned pk2bf(float a, float b) {
    __hip_bfloat162 t = __float22bfloat162_rn(make_float2(a, b));
    union { __hip_bfloat162 h; unsigned u; } c; c.h = t;
    return c.u;
}

__device__ __forceinline__ void gl_lds16(const unsigned short* g, unsigned short* l) {
    __builtin_amdgcn_global_load_lds(
        (const __attribute__((address_space(1))) void*)g,
        (__attribute__((address_space(3))) void*)l,
        16, 0, 0);
}

// ---------------- kernel 1: hidden_states fp32 -> bf16 ----------------
__global__ void cvt_hs_kernel(const float4* __restrict__ in, ushort4* __restrict__ out) {
    int i = blockIdx.x * 256 + threadIdx.x;
    float4 v = in[i];
    ushort4 o;
    o.x = f2bf(v.x); o.y = f2bf(v.y); o.z = f2bf(v.z); o.w = f2bf(v.w);
    out[i] = o;
}

// ---------------- kernel 2: weight transpose+cast (W[k][n] -> Wt[n][k] bf16) ----
__global__ void wtrans_kernel(const float* __restrict__ Wq, const float* __restrict__ Wk,
                              const float* __restrict__ Wv, const float* __restrict__ Wo,
                              unsigned short* __restrict__ Wqkv_t, unsigned short* __restrict__ Wo_t) {
    __shared__ float tile[64][65];
    int mtx = blockIdx.y;
    const float* W = (mtx == 0) ? Wq : (mtx == 1) ? Wk : (mtx == 2) ? Wv : Wo;
    unsigned short* Out = (mtx < 3) ? (Wqkv_t + (size_t)mtx * 1024 * 1024) : Wo_t;
    int tl = blockIdx.x;
    int tx = tl & 15, ty = tl >> 4;
    int t = threadIdx.x;
    int col = t & 63, rb = t >> 6;
#pragma unroll
    for (int rr = 0; rr < 16; ++rr) {
        int r = rb * 16 + rr;
        tile[r][col] = W[(size_t)(ty * 64 + r) * 1024 + tx * 64 + col];
    }
    __syncthreads();
#pragma unroll
    for (int rr = 0; rr < 16; ++rr) {
        int r = rb * 16 + rr;
        Out[(size_t)(tx * 64 + r) * 1024 + ty * 64 + col] = f2bf(tile[col][r]);
    }
}

// ---------------- kernel 3: QKV GEMM (8192x1024 @ 1024x3072) ----------------
// Q -> (b,h,t,d). K -> fragment order Kf[bh][tile=tt>>4][dhalf=dd>>5][lane][j]
// (tile stride 1024, dhalf stride 512), lane=((dd>>3)&3)*16+(tt&15), j=dd&7.
// V -> fragment order Vf[bh][chunk=tt>>5][nd=dd>>4][lane][j],
// lane=((tt>>3)&3)*16+(dd&15), j=tt&7.
__global__ __launch_bounds__(256) void gemm_qkv_kernel(
    const unsigned short* __restrict__ A, const unsigned short* __restrict__ Bt,
    unsigned short* __restrict__ Qg, unsigned short* __restrict__ Kf, unsigned short* __restrict__ Vf) {
    __shared__ __align__(16) unsigned short As[128 * 32];
    __shared__ __align__(16) unsigned short Bs[128 * 32];
    const int tid = threadIdx.x;
    const int w = tid >> 6, lane = tid & 63;
    const int quad = lane >> 4, l16 = lane & 15;
    const int m0 = blockIdx.y * 128, n0 = blockIdx.x * 128;
    const int mw = (w >> 1) * 64, nw = (w & 1) * 64;
    const int K = 1024;
    const int srow = lane >> 2;
    const int scol = (lane & 3) * 8;

    const f32x4 fzero = {0.f, 0.f, 0.f, 0.f};
    f32x4 acc[4][4];
#pragma unroll
    for (int i = 0; i < 4; ++i)
#pragma unroll
        for (int j = 0; j < 4; ++j) acc[i][j] = fzero;

    for (int k0 = 0; k0 < K; k0 += 32) {
        gl_lds16(A + (size_t)(m0 + w * 32 + srow) * K + k0 + scol,       As + (w * 32) * 32);
        gl_lds16(A + (size_t)(m0 + w * 32 + 16 + srow) * K + k0 + scol,  As + (w * 32 + 16) * 32);
        gl_lds16(Bt + (size_t)(n0 + w * 32 + srow) * K + k0 + scol,      Bs + (w * 32) * 32);
        gl_lds16(Bt + (size_t)(n0 + w * 32 + 16 + srow) * K + k0 + scol, Bs + (w * 32 + 16) * 32);
        __syncthreads();
        bf16x8 a[4], b[4];
#pragma unroll
        for (int i = 0; i < 4; ++i)
            a[i] = *(const bf16x8*)(As + (mw + i * 16 + l16) * 32 + quad * 8);
#pragma unroll
        for (int j = 0; j < 4; ++j)
            b[j] = *(const bf16x8*)(Bs + (nw + j * 16 + l16) * 32 + quad * 8);
#pragma unroll
        for (int i = 0; i < 4; ++i)
#pragma unroll
            for (int j = 0; j < 4; ++j)
                acc[i][j] = __builtin_amdgcn_mfma_f32_16x16x32_bf16(a[i], b[j], acc[i][j], 0, 0, 0);
        __syncthreads();
    }

#pragma unroll
    for (int j = 0; j < 4; ++j) {
        int gn = n0 + nw + j * 16 + l16;
        int tensor = gn >> 10;
        int nl = gn & 1023;
        int hh = nl >> 6, dd = nl & 63;
#pragma unroll
        for (int i = 0; i < 4; ++i) {
            int gmb = m0 + mw + i * 16 + quad * 4;
            int bb = gmb >> 11;
            size_t bhh = (size_t)(bb * 16 + hh);
            if (tensor == 0) {
#pragma unroll
                for (int r = 0; r < 4; ++r) {
                    int tt = (gmb + r) & 2047;
                    Qg[(bhh * 2048 + tt) * 64 + dd] = f2bf(acc[i][j][r]);
                }
            } else if (tensor == 1) {
#pragma unroll
                for (int r = 0; r < 4; ++r) {
                    int tt = (gmb + r) & 2047;
                    Kf[bhh * 131072 + (size_t)(tt >> 4) * 1024 + (dd >> 5) * 512 +
                       (((dd >> 3) & 3) * 16 + (tt & 15)) * 8 + (dd & 7)] = f2bf(acc[i][j][r]);
                }
            } else {
                int tt = gmb & 2047;
                ushort4 v4;
                v4.x = f2bf(acc[i][j][0]); v4.y = f2bf(acc[i][j][1]);
                v4.z = f2bf(acc[i][j][2]); v4.w = f2bf(acc[i][j][3]);
                *(ushort4*)(Vf + bhh * 131072 + (size_t)(tt >> 5) * 2048 + (dd >> 4) * 512 +
                            (((tt >> 3) & 3) * 16 + (dd & 15)) * 8 + (tt & 7)) = v4;
            }
        }
    }
}

// ---------------- kernel 4: flash attention (barrier-free, S^T, no online max) ----
// Q: (b,h,t,d) bf16. Kf/Vf: fragment order (see gemm_qkv). AO out: (b,t,h,d) bf16.
// 4 waves/block, each wave owns 16 q-rows; 2048 blocks (8/CU) for TLP.
// K/V frags loaded directly global->VGPR; only P transits per-wave LDS.
__global__ __launch_bounds__(256) void attn_kernel(
    const unsigned short* __restrict__ Qg, const unsigned short* __restrict__ Kf,
    const unsigned short* __restrict__ Vf, const int* __restrict__ mask,
    unsigned short* __restrict__ AO) {
    __shared__ __align__(16) unsigned short Pbuf[4][1024];
    __shared__ float li_lds[4][16];

    const int tid = threadIdx.x;
    const int w = tid >> 6, lane = tid & 63;
    const int quad = lane >> 4, l16 = lane & 15;
    const int bid = blockIdx.x;
    const int bh = bid >> 5;
    const int qt = bid & 31;
    const int b = bh >> 4, h = bh & 15;
    const size_t bh_td = (size_t)bh * (2048 * 64);
    const int q0w = qt * 64 + w * 16;

    // Q fragments (B-operand): [n=q=l16][k=d=quad*8+j], two d-halves
    bf16x8 aq[2];
#pragma unroll
    for (int hh = 0; hh < 2; ++hh)
        aq[hh] = *(const bf16x8*)(Qg + bh_td + (size_t)(q0w + l16) * 64 + hh * 32 + quad * 8);

    const unsigned short* Kp = Kf + bh_td + lane * 8;
    const unsigned short* Vp = Vf + bh_td + lane * 8;
    const int* mrow = mask + b * 2048;

    const f32x4 fzero = {0.f, 0.f, 0.f, 0.f};
    f32x4 po[4];
#pragma unroll
    for (int nd = 0; nd < 4; ++nd) po[nd] = fzero;
    float li = 0.f;

    for (int k0 = 0; k0 < 2048; k0 += 64) {
        const int tb = (k0 >> 4) * 1024;
        // K fragments: A-operand [m=key=l16][k=d=quad*8+j]
        bf16x8 ka0[4], ka1[4];
#pragma unroll
        for (int kt = 0; kt < 4; ++kt) {
            ka0[kt] = *(const bf16x8*)(Kp + tb + kt * 1024);
            ka1[kt] = *(const bf16x8*)(Kp + tb + kt * 1024 + 512);
        }
        // V fragments (issue early; consumed after QK^T/exp): B-operand
        // [n=d=l16(+16*nd)][k=key=quad*8+j]
        bf16x8 bv[2][4];
#pragma unroll
        for (int c = 0; c < 2; ++c)
#pragma unroll
            for (int nd = 0; nd < 4; ++nd)
                bv[c][nd] = *(const bf16x8*)(Vp + ((k0 >> 5) + c) * 2048 + nd * 512);

        // ---- S^T = K @ Q^T per 16-key tile, exp, pack into P fragments ----
#pragma unroll
        for (int kt = 0; kt < 4; ++kt) {
            int4 mv = *(const int4*)(mrow + k0 + kt * 16 + quad * 4);
            float mb0 = mv.x ? 0.f : -1e30f;
            float mb1 = mv.y ? 0.f : -1e30f;
            float mb2 = mv.z ? 0.f : -1e30f;
            float mb3 = mv.w ? 0.f : -1e30f;
            int pidx = ((((kt & 1) << 1) | (quad >> 1)) * 16 + l16) * 8 + (quad & 1) * 4;
            f32x4 st = __builtin_amdgcn_mfma_f32_16x16x32_bf16(ka0[kt], aq[0], fzero, 0, 0, 0);
            st = __builtin_amdgcn_mfma_f32_16x16x32_bf16(ka1[kt], aq[1], st, 0, 0, 0);
            float p0 = __builtin_amdgcn_exp2f(st[0] * SE + mb0);
            float p1 = __builtin_amdgcn_exp2f(st[1] * SE + mb1);
            float p2 = __builtin_amdgcn_exp2f(st[2] * SE + mb2);
            float p3 = __builtin_amdgcn_exp2f(st[3] * SE + mb3);
            li += (p0 + p1) + (p2 + p3);
            uint2 pk; pk.x = pk2bf(p0, p1); pk.y = pk2bf(p2, p3);
            *(uint2*)(Pbuf[w] + (kt >> 1) * 512 + pidx) = pk;
        }

        asm volatile("s_waitcnt lgkmcnt(0)" ::: "memory");

        // ---- PV: O[q][d] += P @ V ----
#pragma unroll
        for (int c = 0; c < 2; ++c) {
            bf16x8 ap = *(const bf16x8*)(Pbuf[w] + c * 512 + lane * 8);
#pragma unroll
            for (int nd = 0; nd < 4; ++nd)
                po[nd] = __builtin_amdgcn_mfma_f32_16x16x32_bf16(ap, bv[c][nd], po[nd], 0, 0, 0);
        }
    }

    // ---- epilogue: reduce li across quads (per-wave), write AO (b,t,h,d) ----
    li += __shfl_xor(li, 16, 64);
    li += __shfl_xor(li, 32, 64);
    if (quad == 0) li_lds[w][l16] = li;
    asm volatile("s_waitcnt lgkmcnt(0)" ::: "memory");
    float linv[4];
#pragma unroll
    for (int r = 0; r < 4; ++r)
        linv[r] = __builtin_amdgcn_rcpf(li_lds[w][quad * 4 + r]);

#pragma unroll
    for (int r = 0; r < 4; ++r) {
        int q = q0w + quad * 4 + r;
        size_t ob = (size_t)(b * 2048 + q) * 1024 + h * 64;
#pragma unroll
        for (int nd = 0; nd < 4; ++nd)
            AO[ob + nd * 16 + l16] = f2bf(po[nd][r] * linv[r]);
    }
}

// ---------------- kernel 5: output GEMM (8192x1024 @ 1024x1024) + bias ----------------
__global__ __launch_bounds__(256) void gemm_out_kernel(
    const unsigned short* __restrict__ A, const unsigned short* __restrict__ Bt,
    const float* __restrict__ bo, float* __restrict__ out) {
    __shared__ __align__(16) unsigned short As[128 * 32];
    __shared__ __align__(16) unsigned short Bs[128 * 32];
    const int tid = threadIdx.x;
    const int w = tid >> 6, lane = tid & 63;
    const int quad = lane >> 4, l16 = lane & 15;
    const int m0 = blockIdx.y * 128, n0 = blockIdx.x * 128;
    const int mw = (w >> 1) * 64, nw = (w & 1) * 64;
    const int K = 1024;
    const int srow = lane >> 2;
    const int scol = (lane & 3) * 8;

    const f32x4 fzero = {0.f, 0.f, 0.f, 0.f};
    f32x4 acc[4][4];
#pragma unroll
    for (int i = 0; i < 4; ++i)
#pragma unroll
        for (int j = 0; j < 4; ++j) acc[i][j] = fzero;

    for (int k0 = 0; k0 < K; k0 += 32) {
        gl_lds16(A + (size_t)(m0 + w * 32 + srow) * K + k0 + scol,       As + (w * 32) * 32);
        gl_lds16(A + (size_t)(m0 + w * 32 + 16 + srow) * K + k0 + scol,  As + (w * 32 + 16) * 32);
        gl_lds16(Bt + (size_t)(n0 + w * 32 + srow) * K + k0 + scol,      Bs + (w * 32) * 32);
        gl_lds16(Bt + (size_t)(n0 + w * 32 + 16 + srow) * K + k0 + scol, Bs + (w * 32 + 16) * 32);
        __syncthreads();
        bf16x8 a[4], b[4];
#pragma unroll
        for (int i = 0; i < 4; ++i)
            a[i] = *(const bf16x8*)(As + (mw + i * 16 + l16) * 32 + quad * 8);
#pragma unroll
        for (int j = 0; j < 4; ++j)
            b[j] = *(const bf16x8*)(Bs + (nw + j * 16 + l16) * 32 + quad * 8);
#pragma unroll
        for (int i = 0; i < 4; ++i)
#pragma unroll
            for (int j = 0; j < 4; ++j)
                acc[i][j] = __builtin_amdgcn_mfma_f32_16x16x32_bf16(a[i], b[j], acc[i][j], 0, 0, 0);
        __syncthreads();
    }

#pragma unroll
    for (int j = 0; j < 4; ++j) {
        int gn = n0 + nw + j * 16 + l16;
        float bias = bo[gn];
#pragma unroll
        for (int i = 0; i < 4; ++i) {
            int gmb = m0 + mw + i * 16 + quad * 4;
#pragma unroll
            for (int r = 0; r < 4; ++r)
                out[(size_t)(gmb + r) * 1024 + gn] = acc[i][j][r] + bias;
        }
    }
}

extern "C" void kernel_launch(void* const* d_in, const int* in_sizes, int n_in,
                              void* d_out, int out_size, void* d_ws, size_t ws_size,
                              hipStream_t stream) {
    const float* hs  = (const float*)d_in[0];
    const int* mask  = (const int*)d_in[1];
    const float* Wq  = (const float*)d_in[2];
    const float* Wk  = (const float*)d_in[3];
    const float* Wv  = (const float*)d_in[4];
    const float* Wo  = (const float*)d_in[5];
    const float* bo  = (const float*)d_in[6];
    float* out = (float*)d_out;

    char* ws = (char*)d_ws;
    unsigned short* hs_bf = (unsigned short*)(ws);                  // 16 MB
    unsigned short* wqkv  = (unsigned short*)(ws + 16777216);       // 6 MB
    unsigned short* wo_t  = (unsigned short*)(ws + 23068672);       // 2 MB
    unsigned short* Qg    = (unsigned short*)(ws + 25165824);       // 16 MB
    unsigned short* Kf    = (unsigned short*)(ws + 41943040);       // 16 MB
    unsigned short* Vf    = (unsigned short*)(ws + 58720256);       // 16 MB
    unsigned short* AO    = (unsigned short*)(ws + 75497472);       // 16 MB

    cvt_hs_kernel<<<8192, 256, 0, stream>>>((const float4*)hs, (ushort4*)hs_bf);
    wtrans_kernel<<<dim3(256, 4), 256, 0, stream>>>(Wq, Wk, Wv, Wo, wqkv, wo_t);
    gemm_qkv_kernel<<<dim3(24, 64), 256, 0, stream>>>(hs_bf, wqkv, Qg, Kf, Vf);
    attn_kernel<<<2048, 256, 0, stream>>>(Qg, Kf, Vf, mask, AO);
    gemm_out_kernel<<<dim3(8, 64), 256, 0, stream>>>(AO, wo_t, bo, out);
}

// Round 6
// 304.751 us; speedup vs baseline: 1.1614x; 1.1614x over previous
//
#include <hip/hip_runtime.h>
#include <hip/hip_bf16.h>

#define B_ 4
#define T_ 2048
#define C_ 1024
#define H_ 16
#define D_ 64
#define SCALE_ 0.125f
#define L2E 1.4426950408889634f
#define SE (SCALE_ * L2E)

typedef __attribute__((ext_vector_type(8))) short bf16x8;
typedef __attribute__((ext_vector_type(4))) float f32x4;

__device__ __forceinline__ unsigned short f2bf(float f) {
    union { float f; unsigned u; } v; v.f = f;
    unsigned r = v.u + 0x7fff + ((v.u >> 16) & 1);
    return (unsigned short)(r >> 16);
}

__device__ __forceinline__ unsigned pk2bf(float a, float b) {
    __hip_bfloat162 t = __float22bfloat162_rn(make_float2(a, b));
    union { __hip_bfloat162 h; unsigned u; } c; c.h = t;
    return c.u;
}

__device__ __forceinline__ void gl_lds16(const unsigned short* g, unsigned short* l) {
    __builtin_amdgcn_global_load_lds(
        (const __attribute__((address_space(1))) void*)g,
        (__attribute__((address_space(3))) void*)l,
        16, 0, 0);
}

// ---------------- kernel 1: hidden_states fp32 -> bf16 ----------------
__global__ void cvt_hs_kernel(const float4* __restrict__ in, ushort4* __restrict__ out) {
    int i = blockIdx.x * 256 + threadIdx.x;
    float4 v = in[i];
    ushort4 o;
    o.x = f2bf(v.x); o.y = f2bf(v.y); o.z = f2bf(v.z); o.w = f2bf(v.w);
    out[i] = o;
}

// ---------------- kernel 2: weight transpose+cast (W[k][n] -> Wt[n][k] bf16) ----
__global__ void wtrans_kernel(const float* __restrict__ Wq, const float* __restrict__ Wk,
                              const float* __restrict__ Wv, const float* __restrict__ Wo,
                              unsigned short* __restrict__ Wqkv_t, unsigned short* __restrict__ Wo_t) {
    __shared__ float tile[64][65];
    int mtx = blockIdx.y;
    const float* W = (mtx == 0) ? Wq : (mtx == 1) ? Wk : (mtx == 2) ? Wv : Wo;
    unsigned short* Out = (mtx < 3) ? (Wqkv_t + (size_t)mtx * 1024 * 1024) : Wo_t;
    int tl = blockIdx.x;
    int tx = tl & 15, ty = tl >> 4;
    int t = threadIdx.x;
    int col = t & 63, rb = t >> 6;
#pragma unroll
    for (int rr = 0; rr < 16; ++rr) {
        int r = rb * 16 + rr;
        tile[r][col] = W[(size_t)(ty * 64 + r) * 1024 + tx * 64 + col];
    }
    __syncthreads();
#pragma unroll
    for (int rr = 0; rr < 16; ++rr) {
        int r = rb * 16 + rr;
        Out[(size_t)(tx * 64 + r) * 1024 + ty * 64 + col] = f2bf(tile[col][r]);
    }
}

// ---------------- kernel 3: QKV GEMM (8192x1024 @ 1024x3072) ----------------
// Q -> (b,h,t,d). K -> fragment order Kf[bh][tile=tt>>4][dhalf=dd>>5][lane][j]
// (tile stride 1024, dhalf stride 512), lane=((dd>>3)&3)*16+(tt&15), j=dd&7.
// V -> fragment order Vf[bh][chunk=tt>>5][nd=dd>>4][lane][j],
// lane=((tt>>3)&3)*16+(dd&15), j=tt&7.
__global__ __launch_bounds__(256) void gemm_qkv_kernel(
    const unsigned short* __restrict__ A, const unsigned short* __restrict__ Bt,
    unsigned short* __restrict__ Qg, unsigned short* __restrict__ Kf, unsigned short* __restrict__ Vf) {
    __shared__ __align__(16) unsigned short As[128 * 32];
    __shared__ __align__(16) unsigned short Bs[128 * 32];
    const int tid = threadIdx.x;
    const int w = tid >> 6, lane = tid & 63;
    const int quad = lane >> 4, l16 = lane & 15;
    const int m0 = blockIdx.y * 128, n0 = blockIdx.x * 128;
    const int mw = (w >> 1) * 64, nw = (w & 1) * 64;
    const int K = 1024;
    const int srow = lane >> 2;
    const int scol = (lane & 3) * 8;

    const f32x4 fzero = {0.f, 0.f, 0.f, 0.f};
    f32x4 acc[4][4];
#pragma unroll
    for (int i = 0; i < 4; ++i)
#pragma unroll
        for (int j = 0; j < 4; ++j) acc[i][j] = fzero;

    for (int k0 = 0; k0 < K; k0 += 32) {
        gl_lds16(A + (size_t)(m0 + w * 32 + srow) * K + k0 + scol,       As + (w * 32) * 32);
        gl_lds16(A + (size_t)(m0 + w * 32 + 16 + srow) * K + k0 + scol,  As + (w * 32 + 16) * 32);
        gl_lds16(Bt + (size_t)(n0 + w * 32 + srow) * K + k0 + scol,      Bs + (w * 32) * 32);
        gl_lds16(Bt + (size_t)(n0 + w * 32 + 16 + srow) * K + k0 + scol, Bs + (w * 32 + 16) * 32);
        __syncthreads();
        bf16x8 a[4], b[4];
#pragma unroll
        for (int i = 0; i < 4; ++i)
            a[i] = *(const bf16x8*)(As + (mw + i * 16 + l16) * 32 + quad * 8);
#pragma unroll
        for (int j = 0; j < 4; ++j)
            b[j] = *(const bf16x8*)(Bs + (nw + j * 16 + l16) * 32 + quad * 8);
#pragma unroll
        for (int i = 0; i < 4; ++i)
#pragma unroll
            for (int j = 0; j < 4; ++j)
                acc[i][j] = __builtin_amdgcn_mfma_f32_16x16x32_bf16(a[i], b[j], acc[i][j], 0, 0, 0);
        __syncthreads();
    }

#pragma unroll
    for (int j = 0; j < 4; ++j) {
        int gn = n0 + nw + j * 16 + l16;
        int tensor = gn >> 10;
        int nl = gn & 1023;
        int hh = nl >> 6, dd = nl & 63;
#pragma unroll
        for (int i = 0; i < 4; ++i) {
            int gmb = m0 + mw + i * 16 + quad * 4;
            int bb = gmb >> 11;
            size_t bhh = (size_t)(bb * 16 + hh);
            if (tensor == 0) {
#pragma unroll
                for (int r = 0; r < 4; ++r) {
                    int tt = (gmb + r) & 2047;
                    Qg[(bhh * 2048 + tt) * 64 + dd] = f2bf(acc[i][j][r]);
                }
            } else if (tensor == 1) {
#pragma unroll
                for (int r = 0; r < 4; ++r) {
                    int tt = (gmb + r) & 2047;
                    Kf[bhh * 131072 + (size_t)(tt >> 4) * 1024 + (dd >> 5) * 512 +
                       (((dd >> 3) & 3) * 16 + (tt & 15)) * 8 + (dd & 7)] = f2bf(acc[i][j][r]);
                }
            } else {
                int tt = gmb & 2047;
                ushort4 v4;
                v4.x = f2bf(acc[i][j][0]); v4.y = f2bf(acc[i][j][1]);
                v4.z = f2bf(acc[i][j][2]); v4.w = f2bf(acc[i][j][3]);
                *(ushort4*)(Vf + bhh * 131072 + (size_t)(tt >> 5) * 2048 + (dd >> 4) * 512 +
                            (((tt >> 3) & 3) * 16 + (dd & 15)) * 8 + (tt & 7)) = v4;
            }
        }
    }
}

// ---------------- kernel 4: flash attention (barrier-free, S^T, no online max) ----
// R3 structure (32 q-rows/wave, 2 qi chains, 1024 blocks) plus:
//  - XCD swizzle: all 16 q-blocks of one (b,h) share bid%8 -> same XCD L2;
//    per-XCD K/V working set = 8 bh x 512KB = 4MB = L2 size.
//  - V fragment loads hoisted to loop top (latency hidden under QK/exp).
__global__ __launch_bounds__(256) void attn_kernel(
    const unsigned short* __restrict__ Qg, const unsigned short* __restrict__ Kf,
    const unsigned short* __restrict__ Vf, const int* __restrict__ mask,
    unsigned short* __restrict__ AO) {
    __shared__ __align__(16) unsigned short Pbuf[4][2048];
    __shared__ float li_lds[4][32];

    const int tid = threadIdx.x;
    const int w = tid >> 6, lane = tid & 63;
    const int quad = lane >> 4, l16 = lane & 15;
    const int bid = blockIdx.x;
    // swizzle: bid bits [2:0]=bh_hi, [6:3]=qt, [9:7]=bh_lo
    const int bh = (bid & 7) * 8 + ((bid >> 7) & 7);
    const int qt = (bid >> 3) & 15;
    const int b = bh >> 4, h = bh & 15;
    const size_t bh_td = (size_t)bh * (2048 * 64);
    const int q0w = qt * 128 + w * 32;

    // Q fragments (B-operand): [n=q=l16][k=d=quad*8+j]
    bf16x8 aq[2][2];
#pragma unroll
    for (int qi = 0; qi < 2; ++qi)
#pragma unroll
        for (int hh = 0; hh < 2; ++hh)
            aq[qi][hh] = *(const bf16x8*)(Qg + bh_td + (size_t)(q0w + qi * 16 + l16) * 64 + hh * 32 + quad * 8);

    const unsigned short* Kp = Kf + bh_td + lane * 8;
    const unsigned short* Vp = Vf + bh_td + lane * 8;
    const int* mrow = mask + b * 2048;

    const f32x4 fzero = {0.f, 0.f, 0.f, 0.f};
    f32x4 po[2][4];
#pragma unroll
    for (int qi = 0; qi < 2; ++qi)
#pragma unroll
        for (int nd = 0; nd < 4; ++nd) po[qi][nd] = fzero;
    float li[2] = {0.f, 0.f};

    for (int k0 = 0; k0 < 2048; k0 += 64) {
        const int tb = (k0 >> 4) * 1024;
        // K fragments: A-operand [m=key=l16][k=d=quad*8+j]
        bf16x8 ka0[4], ka1[4];
#pragma unroll
        for (int kt = 0; kt < 4; ++kt) {
            ka0[kt] = *(const bf16x8*)(Kp + tb + kt * 1024);
            ka1[kt] = *(const bf16x8*)(Kp + tb + kt * 1024 + 512);
        }
        // V fragments (issued early, consumed at the end): B-operand
        // [n=d=l16(+16*nd)][k=key=quad*8+j]
        bf16x8 bv[2][4];
#pragma unroll
        for (int c = 0; c < 2; ++c)
#pragma unroll
            for (int nd = 0; nd < 4; ++nd)
                bv[c][nd] = *(const bf16x8*)(Vp + ((k0 >> 5) + c) * 2048 + nd * 512);

        // ---- S^T = K @ Q^T per 16-key tile, exp, pack into P fragments ----
#pragma unroll
        for (int kt = 0; kt < 4; ++kt) {
            int4 mv = *(const int4*)(mrow + k0 + kt * 16 + quad * 4);
            float mb0 = mv.x ? 0.f : -1e30f;
            float mb1 = mv.y ? 0.f : -1e30f;
            float mb2 = mv.z ? 0.f : -1e30f;
            float mb3 = mv.w ? 0.f : -1e30f;
            int pidx = ((((kt & 1) << 1) | (quad >> 1)) * 16 + l16) * 8 + (quad & 1) * 4;
#pragma unroll
            for (int qi = 0; qi < 2; ++qi) {
                f32x4 st = __builtin_amdgcn_mfma_f32_16x16x32_bf16(ka0[kt], aq[qi][0], fzero, 0, 0, 0);
                st = __builtin_amdgcn_mfma_f32_16x16x32_bf16(ka1[kt], aq[qi][1], st, 0, 0, 0);
                float p0 = __builtin_amdgcn_exp2f(st[0] * SE + mb0);
                float p1 = __builtin_amdgcn_exp2f(st[1] * SE + mb1);
                float p2 = __builtin_amdgcn_exp2f(st[2] * SE + mb2);
                float p3 = __builtin_amdgcn_exp2f(st[3] * SE + mb3);
                li[qi] += (p0 + p1) + (p2 + p3);
                uint2 pk; pk.x = pk2bf(p0, p1); pk.y = pk2bf(p2, p3);
                *(uint2*)(Pbuf[w] + (qi * 2 + (kt >> 1)) * 512 + pidx) = pk;
            }
        }

        asm volatile("s_waitcnt lgkmcnt(0)" ::: "memory");

        // ---- PV: O[q][d] += P @ V ----
#pragma unroll
        for (int c = 0; c < 2; ++c)
#pragma unroll
            for (int qi = 0; qi < 2; ++qi) {
                bf16x8 ap = *(const bf16x8*)(Pbuf[w] + (qi * 2 + c) * 512 + lane * 8);
#pragma unroll
                for (int nd = 0; nd < 4; ++nd)
                    po[qi][nd] = __builtin_amdgcn_mfma_f32_16x16x32_bf16(ap, bv[c][nd], po[qi][nd], 0, 0, 0);
            }
    }

    // ---- epilogue: reduce li across quads (per-wave), write AO (b,t,h,d) ----
#pragma unroll
    for (int qi = 0; qi < 2; ++qi) {
        li[qi] += __shfl_xor(li[qi], 16, 64);
        li[qi] += __shfl_xor(li[qi], 32, 64);
        if (quad == 0) li_lds[w][qi * 16 + l16] = li[qi];
    }
    asm volatile("s_waitcnt lgkmcnt(0)" ::: "memory");
    float linv[2][4];
#pragma unroll
    for (int qi = 0; qi < 2; ++qi)
#pragma unroll
        for (int r = 0; r < 4; ++r)
            linv[qi][r] = __builtin_amdgcn_rcpf(li_lds[w][qi * 16 + quad * 4 + r]);

#pragma unroll
    for (int qi = 0; qi < 2; ++qi)
#pragma unroll
        for (int r = 0; r < 4; ++r) {
            int q = q0w + qi * 16 + quad * 4 + r;
            size_t ob = (size_t)(b * 2048 + q) * 1024 + h * 64;
#pragma unroll
            for (int nd = 0; nd < 4; ++nd)
                AO[ob + nd * 16 + l16] = f2bf(po[qi][nd][r] * linv[qi][r]);
        }
}

// ---------------- kernel 5: output GEMM (8192x1024 @ 1024x1024) + bias ----------------
__global__ __launch_bounds__(256) void gemm_out_kernel(
    const unsigned short* __restrict__ A, const unsigned short* __restrict__ Bt,
    const float* __restrict__ bo, float* __restrict__ out) {
    __shared__ __align__(16) unsigned short As[128 * 32];
    __shared__ __align__(16) unsigned short Bs[128 * 32];
    const int tid = threadIdx.x;
    const int w = tid >> 6, lane = tid & 63;
    const int quad = lane >> 4, l16 = lane & 15;
    const int m0 = blockIdx.y * 128, n0 = blockIdx.x * 128;
    const int mw = (w >> 1) * 64, nw = (w & 1) * 64;
    const int K = 1024;
    const int srow = lane >> 2;
    const int scol = (lane & 3) * 8;

    const f32x4 fzero = {0.f, 0.f, 0.f, 0.f};
    f32x4 acc[4][4];
#pragma unroll
    for (int i = 0; i < 4; ++i)
#pragma unroll
        for (int j = 0; j < 4; ++j) acc[i][j] = fzero;

    for (int k0 = 0; k0 < K; k0 += 32) {
        gl_lds16(A + (size_t)(m0 + w * 32 + srow) * K + k0 + scol,       As + (w * 32) * 32);
        gl_lds16(A + (size_t)(m0 + w * 32 + 16 + srow) * K + k0 + scol,  As + (w * 32 + 16) * 32);
        gl_lds16(Bt + (size_t)(n0 + w * 32 + srow) * K + k0 + scol,      Bs + (w * 32) * 32);
        gl_lds16(Bt + (size_t)(n0 + w * 32 + 16 + srow) * K + k0 + scol, Bs + (w * 32 + 16) * 32);
        __syncthreads();
        bf16x8 a[4], b[4];
#pragma unroll
        for (int i = 0; i < 4; ++i)
            a[i] = *(const bf16x8*)(As + (mw + i * 16 + l16) * 32 + quad * 8);
#pragma unroll
        for (int j = 0; j < 4; ++j)
            b[j] = *(const bf16x8*)(Bs + (nw + j * 16 + l16) * 32 + quad * 8);
#pragma unroll
        for (int i = 0; i < 4; ++i)
#pragma unroll
            for (int j = 0; j < 4; ++j)
                acc[i][j] = __builtin_amdgcn_mfma_f32_16x16x32_bf16(a[i], b[j], acc[i][j], 0, 0, 0);
        __syncthreads();
    }

#pragma unroll
    for (int j = 0; j < 4; ++j) {
        int gn = n0 + nw + j * 16 + l16;
        float bias = bo[gn];
#pragma unroll
        for (int i = 0; i < 4; ++i) {
            int gmb = m0 + mw + i * 16 + quad * 4;
#pragma unroll
            for (int r = 0; r < 4; ++r)
                out[(size_t)(gmb + r) * 1024 + gn] = acc[i][j][r] + bias;
        }
    }
}

extern "C" void kernel_launch(void* const* d_in, const int* in_sizes, int n_in,
                              void* d_out, int out_size, void* d_ws, size_t ws_size,
                              hipStream_t stream) {
    const float* hs  = (const float*)d_in[0];
    const int* mask  = (const int*)d_in[1];
    const float* Wq  = (const float*)d_in[2];
    const float* Wk  = (const float*)d_in[3];
    const float* Wv  = (const float*)d_in[4];
    const float* Wo  = (const float*)d_in[5];
    const float* bo  = (const float*)d_in[6];
    float* out = (float*)d_out;

    char* ws = (char*)d_ws;
    unsigned short* hs_bf = (unsigned short*)(ws);                  // 16 MB
    unsigned short* wqkv  = (unsigned short*)(ws + 16777216);       // 6 MB
    unsigned short* wo_t  = (unsigned short*)(ws + 23068672);       // 2 MB
    unsigned short* Qg    = (unsigned short*)(ws + 25165824);       // 16 MB
    unsigned short* Kf    = (unsigned short*)(ws + 41943040);       // 16 MB
    unsigned short* Vf    = (unsigned short*)(ws + 58720256);       // 16 MB
    unsigned short* AO    = (unsigned short*)(ws + 75497472);       // 16 MB

    cvt_hs_kernel<<<8192, 256, 0, stream>>>((const float4*)hs, (ushort4*)hs_bf);
    wtrans_kernel<<<dim3(256, 4), 256, 0, stream>>>(Wq, Wk, Wv, Wo, wqkv, wo_t);
    gemm_qkv_kernel<<<dim3(24, 64), 256, 0, stream>>>(hs_bf, wqkv, Qg, Kf, Vf);
    attn_kernel<<<1024, 256, 0, stream>>>(Qg, Kf, Vf, mask, AO);
    gemm_out_kernel<<<dim3(8, 64), 256, 0, stream>>>(AO, wo_t, bo, out);
}

// Round 7
// 296.460 us; speedup vs baseline: 1.1939x; 1.0280x over previous
//
#include <hip/hip_runtime.h>
#include <hip/hip_bf16.h>

#define B_ 4
#define T_ 2048
#define C_ 1024
#define H_ 16
#define D_ 64
#define SCALE_ 0.125f
#define L2E 1.4426950408889634f
#define SE (SCALE_ * L2E)

typedef __attribute__((ext_vector_type(8))) short bf16x8;
typedef __attribute__((ext_vector_type(4))) float f32x4;

__device__ __forceinline__ unsigned short f2bf(float f) {
    union { float f; unsigned u; } v; v.f = f;
    unsigned r = v.u + 0x7fff + ((v.u >> 16) & 1);
    return (unsigned short)(r >> 16);
}

__device__ __forceinline__ unsigned pk2bf(float a, float b) {
    __hip_bfloat162 t = __float22bfloat162_rn(make_float2(a, b));
    union { __hip_bfloat162 h; unsigned u; } c; c.h = t;
    return c.u;
}

__device__ __forceinline__ void gl_lds16(const unsigned short* g, unsigned short* l) {
    __builtin_amdgcn_global_load_lds(
        (const __attribute__((address_space(1))) void*)g,
        (__attribute__((address_space(3))) void*)l,
        16, 0, 0);
}

// ---------------- kernel 1: hidden_states fp32 -> bf16 ----------------
__global__ void cvt_hs_kernel(const float4* __restrict__ in, ushort4* __restrict__ out) {
    int i = blockIdx.x * 256 + threadIdx.x;
    float4 v = in[i];
    ushort4 o;
    o.x = f2bf(v.x); o.y = f2bf(v.y); o.z = f2bf(v.z); o.w = f2bf(v.w);
    out[i] = o;
}

// ---------------- kernel 2: weight transpose+cast (W[k][n] -> Wt[n][k] bf16) ----
__global__ void wtrans_kernel(const float* __restrict__ Wq, const float* __restrict__ Wk,
                              const float* __restrict__ Wv, const float* __restrict__ Wo,
                              unsigned short* __restrict__ Wqkv_t, unsigned short* __restrict__ Wo_t) {
    __shared__ float tile[64][65];
    int mtx = blockIdx.y;
    const float* W = (mtx == 0) ? Wq : (mtx == 1) ? Wk : (mtx == 2) ? Wv : Wo;
    unsigned short* Out = (mtx < 3) ? (Wqkv_t + (size_t)mtx * 1024 * 1024) : Wo_t;
    int tl = blockIdx.x;
    int tx = tl & 15, ty = tl >> 4;
    int t = threadIdx.x;
    int col = t & 63, rb = t >> 6;
#pragma unroll
    for (int rr = 0; rr < 16; ++rr) {
        int r = rb * 16 + rr;
        tile[r][col] = W[(size_t)(ty * 64 + r) * 1024 + tx * 64 + col];
    }
    __syncthreads();
#pragma unroll
    for (int rr = 0; rr < 16; ++rr) {
        int r = rb * 16 + rr;
        Out[(size_t)(tx * 64 + r) * 1024 + ty * 64 + col] = f2bf(tile[col][r]);
    }
}

// ---------------- kernel 3: QKV GEMM (8192x1024 @ 1024x3072) ----------------
// Q -> (b,h,t,d), PRE-SCALED by SCALE*log2e. K -> fragment order
// Kf[bh][tile=tt>>4][dhalf=dd>>5][lane][j] (tile stride 1024, dhalf 512),
// lane=((dd>>3)&3)*16+(tt&15), j=dd&7. V -> Vf[bh][chunk=tt>>5][nd=dd>>4][lane][j],
// lane=((tt>>3)&3)*16+(dd&15), j=tt&7.
__global__ __launch_bounds__(256) void gemm_qkv_kernel(
    const unsigned short* __restrict__ A, const unsigned short* __restrict__ Bt,
    unsigned short* __restrict__ Qg, unsigned short* __restrict__ Kf, unsigned short* __restrict__ Vf) {
    __shared__ __align__(16) unsigned short As[128 * 32];
    __shared__ __align__(16) unsigned short Bs[128 * 32];
    const int tid = threadIdx.x;
    const int w = tid >> 6, lane = tid & 63;
    const int quad = lane >> 4, l16 = lane & 15;
    const int m0 = blockIdx.y * 128, n0 = blockIdx.x * 128;
    const int mw = (w >> 1) * 64, nw = (w & 1) * 64;
    const int K = 1024;
    const int srow = lane >> 2;
    const int scol = (lane & 3) * 8;

    const f32x4 fzero = {0.f, 0.f, 0.f, 0.f};
    f32x4 acc[4][4];
#pragma unroll
    for (int i = 0; i < 4; ++i)
#pragma unroll
        for (int j = 0; j < 4; ++j) acc[i][j] = fzero;

    for (int k0 = 0; k0 < K; k0 += 32) {
        gl_lds16(A + (size_t)(m0 + w * 32 + srow) * K + k0 + scol,       As + (w * 32) * 32);
        gl_lds16(A + (size_t)(m0 + w * 32 + 16 + srow) * K + k0 + scol,  As + (w * 32 + 16) * 32);
        gl_lds16(Bt + (size_t)(n0 + w * 32 + srow) * K + k0 + scol,      Bs + (w * 32) * 32);
        gl_lds16(Bt + (size_t)(n0 + w * 32 + 16 + srow) * K + k0 + scol, Bs + (w * 32 + 16) * 32);
        __syncthreads();
        bf16x8 a[4], b[4];
#pragma unroll
        for (int i = 0; i < 4; ++i)
            a[i] = *(const bf16x8*)(As + (mw + i * 16 + l16) * 32 + quad * 8);
#pragma unroll
        for (int j = 0; j < 4; ++j)
            b[j] = *(const bf16x8*)(Bs + (nw + j * 16 + l16) * 32 + quad * 8);
#pragma unroll
        for (int i = 0; i < 4; ++i)
#pragma unroll
            for (int j = 0; j < 4; ++j)
                acc[i][j] = __builtin_amdgcn_mfma_f32_16x16x32_bf16(a[i], b[j], acc[i][j], 0, 0, 0);
        __syncthreads();
    }

#pragma unroll
    for (int j = 0; j < 4; ++j) {
        int gn = n0 + nw + j * 16 + l16;
        int tensor = gn >> 10;
        int nl = gn & 1023;
        int hh = nl >> 6, dd = nl & 63;
#pragma unroll
        for (int i = 0; i < 4; ++i) {
            int gmb = m0 + mw + i * 16 + quad * 4;
            int bb = gmb >> 11;
            size_t bhh = (size_t)(bb * 16 + hh);
            if (tensor == 0) {
#pragma unroll
                for (int r = 0; r < 4; ++r) {
                    int tt = (gmb + r) & 2047;
                    Qg[(bhh * 2048 + tt) * 64 + dd] = f2bf(acc[i][j][r] * SE);
                }
            } else if (tensor == 1) {
#pragma unroll
                for (int r = 0; r < 4; ++r) {
                    int tt = (gmb + r) & 2047;
                    Kf[bhh * 131072 + (size_t)(tt >> 4) * 1024 + (dd >> 5) * 512 +
                       (((dd >> 3) & 3) * 16 + (tt & 15)) * 8 + (dd & 7)] = f2bf(acc[i][j][r]);
                }
            } else {
                int tt = gmb & 2047;
                ushort4 v4;
                v4.x = f2bf(acc[i][j][0]); v4.y = f2bf(acc[i][j][1]);
                v4.z = f2bf(acc[i][j][2]); v4.w = f2bf(acc[i][j][3]);
                *(ushort4*)(Vf + bhh * 131072 + (size_t)(tt >> 5) * 2048 + (dd >> 4) * 512 +
                            (((tt >> 3) & 3) * 16 + (dd & 15)) * 8 + (tt & 7)) = v4;
            }
        }
    }
}

// ---------------- kernel 4: flash attention (barrier-free, S^T, no online max) ----
// Q (pre-scaled by SCALE*log2e): (b,h,t,d). Kf/Vf: fragment order. AO: (b,t,h,d).
// XCD swizzle keeps all 16 q-blocks of a (b,h) on one XCD's L2.
// Fast path (wave-uniform all-unmasked): p = exp2(raw MFMA output) — no fma/cndmask.
// li accumulated via ones-column MFMA -> same C layout as po -> shuffle-free epilogue.
__global__ __launch_bounds__(256) void attn_kernel(
    const unsigned short* __restrict__ Qg, const unsigned short* __restrict__ Kf,
    const unsigned short* __restrict__ Vf, const int* __restrict__ mask,
    unsigned short* __restrict__ AO) {
    __shared__ __align__(16) unsigned short Pbuf[4][2048];

    const int tid = threadIdx.x;
    const int w = tid >> 6, lane = tid & 63;
    const int quad = lane >> 4, l16 = lane & 15;
    const int bid = blockIdx.x;
    // swizzle: bid bits [2:0]=bh_hi (XCD id), [6:3]=qt, [9:7]=bh_lo
    const int bh = (bid & 7) * 8 + ((bid >> 7) & 7);
    const int qt = (bid >> 3) & 15;
    const int b = bh >> 4, h = bh & 15;
    const size_t bh_td = (size_t)bh * (2048 * 64);
    const int q0w = qt * 128 + w * 32;

    // Q fragments (B-operand): [n=q=l16][k=d=quad*8+j]
    bf16x8 aq[2][2];
#pragma unroll
    for (int qi = 0; qi < 2; ++qi)
#pragma unroll
        for (int hh = 0; hh < 2; ++hh)
            aq[qi][hh] = *(const bf16x8*)(Qg + bh_td + (size_t)(q0w + qi * 16 + l16) * 64 + hh * 32 + quad * 8);

    const unsigned short* Kp = Kf + bh_td + lane * 8;
    const unsigned short* Vp = Vf + bh_td + lane * 8;
    const int* mrow = mask + b * 2048;

    bf16x8 vones;
#pragma unroll
    for (int i = 0; i < 8; ++i) vones[i] = (short)0x3F80;  // bf16 1.0

    const f32x4 fzero = {0.f, 0.f, 0.f, 0.f};
    f32x4 po[2][4];
    f32x4 pl[2];
#pragma unroll
    for (int qi = 0; qi < 2; ++qi) {
        pl[qi] = fzero;
#pragma unroll
        for (int nd = 0; nd < 4; ++nd) po[qi][nd] = fzero;
    }

    for (int k0 = 0; k0 < 2048; k0 += 64) {
        const int tb = (k0 >> 4) * 1024;
        // K fragments: A-operand [m=key=l16][k=d=quad*8+j]
        bf16x8 ka0[4], ka1[4];
#pragma unroll
        for (int kt = 0; kt < 4; ++kt) {
            ka0[kt] = *(const bf16x8*)(Kp + tb + kt * 1024);
            ka1[kt] = *(const bf16x8*)(Kp + tb + kt * 1024 + 512);
        }

        int mk = mrow[k0 + lane];
        bool allok = (__ballot(mk != 0) == 0xFFFFFFFFFFFFFFFFull);

        if (allok) {
            // ---- fast path: p = exp2(st) directly ----
#pragma unroll
            for (int kt = 0; kt < 4; ++kt) {
                int pidx = ((((kt & 1) << 1) | (quad >> 1)) * 16 + l16) * 8 + (quad & 1) * 4;
#pragma unroll
                for (int qi = 0; qi < 2; ++qi) {
                    f32x4 st = __builtin_amdgcn_mfma_f32_16x16x32_bf16(ka0[kt], aq[qi][0], fzero, 0, 0, 0);
                    st = __builtin_amdgcn_mfma_f32_16x16x32_bf16(ka1[kt], aq[qi][1], st, 0, 0, 0);
                    float p0 = __builtin_amdgcn_exp2f(st[0]);
                    float p1 = __builtin_amdgcn_exp2f(st[1]);
                    float p2 = __builtin_amdgcn_exp2f(st[2]);
                    float p3 = __builtin_amdgcn_exp2f(st[3]);
                    uint2 pk; pk.x = pk2bf(p0, p1); pk.y = pk2bf(p2, p3);
                    *(uint2*)(Pbuf[w] + (qi * 2 + (kt >> 1)) * 512 + pidx) = pk;
                }
            }
        } else {
            // ---- slow path: additive mask bias ----
#pragma unroll
            for (int kt = 0; kt < 4; ++kt) {
                int4 mv = *(const int4*)(mrow + k0 + kt * 16 + quad * 4);
                float mb0 = mv.x ? 0.f : -1e30f;
                float mb1 = mv.y ? 0.f : -1e30f;
                float mb2 = mv.z ? 0.f : -1e30f;
                float mb3 = mv.w ? 0.f : -1e30f;
                int pidx = ((((kt & 1) << 1) | (quad >> 1)) * 16 + l16) * 8 + (quad & 1) * 4;
#pragma unroll
                for (int qi = 0; qi < 2; ++qi) {
                    f32x4 st = __builtin_amdgcn_mfma_f32_16x16x32_bf16(ka0[kt], aq[qi][0], fzero, 0, 0, 0);
                    st = __builtin_amdgcn_mfma_f32_16x16x32_bf16(ka1[kt], aq[qi][1], st, 0, 0, 0);
                    float p0 = __builtin_amdgcn_exp2f(st[0] + mb0);
                    float p1 = __builtin_amdgcn_exp2f(st[1] + mb1);
                    float p2 = __builtin_amdgcn_exp2f(st[2] + mb2);
                    float p3 = __builtin_amdgcn_exp2f(st[3] + mb3);
                    uint2 pk; pk.x = pk2bf(p0, p1); pk.y = pk2bf(p2, p3);
                    *(uint2*)(Pbuf[w] + (qi * 2 + (kt >> 1)) * 512 + pidx) = pk;
                }
            }
        }

        // V fragments: B-operand [n=d=l16(+16*nd)][k=key=quad*8+j]
        bf16x8 bv[2][4];
#pragma unroll
        for (int c = 0; c < 2; ++c)
#pragma unroll
            for (int nd = 0; nd < 4; ++nd)
                bv[c][nd] = *(const bf16x8*)(Vp + ((k0 >> 5) + c) * 2048 + nd * 512);

        asm volatile("s_waitcnt lgkmcnt(0)" ::: "memory");

        // ---- PV: O[q][d] += P @ V ; li via ones-column MFMA ----
#pragma unroll
        for (int c = 0; c < 2; ++c)
#pragma unroll
            for (int qi = 0; qi < 2; ++qi) {
                bf16x8 ap = *(const bf16x8*)(Pbuf[w] + (qi * 2 + c) * 512 + lane * 8);
#pragma unroll
                for (int nd = 0; nd < 4; ++nd)
                    po[qi][nd] = __builtin_amdgcn_mfma_f32_16x16x32_bf16(ap, bv[c][nd], po[qi][nd], 0, 0, 0);
                pl[qi] = __builtin_amdgcn_mfma_f32_16x16x32_bf16(ap, vones, pl[qi], 0, 0, 0);
            }
    }

    // ---- epilogue: pl has same C layout as po -> direct normalize & store ----
#pragma unroll
    for (int qi = 0; qi < 2; ++qi)
#pragma unroll
        for (int r = 0; r < 4; ++r) {
            float linv = __builtin_amdgcn_rcpf(pl[qi][r]);
            int q = q0w + qi * 16 + quad * 4 + r;
            size_t ob = (size_t)(b * 2048 + q) * 1024 + h * 64;
#pragma unroll
            for (int nd = 0; nd < 4; ++nd)
                AO[ob + nd * 16 + l16] = f2bf(po[qi][nd][r] * linv);
        }
}

// ---------------- kernel 5: output GEMM (8192x1024 @ 1024x1024) + bias ----------------
__global__ __launch_bounds__(256) void gemm_out_kernel(
    const unsigned short* __restrict__ A, const unsigned short* __restrict__ Bt,
    const float* __restrict__ bo, float* __restrict__ out) {
    __shared__ __align__(16) unsigned short As[128 * 32];
    __shared__ __align__(16) unsigned short Bs[128 * 32];
    const int tid = threadIdx.x;
    const int w = tid >> 6, lane = tid & 63;
    const int quad = lane >> 4, l16 = lane & 15;
    const int m0 = blockIdx.y * 128, n0 = blockIdx.x * 128;
    const int mw = (w >> 1) * 64, nw = (w & 1) * 64;
    const int K = 1024;
    const int srow = lane >> 2;
    const int scol = (lane & 3) * 8;

    const f32x4 fzero = {0.f, 0.f, 0.f, 0.f};
    f32x4 acc[4][4];
#pragma unroll
    for (int i = 0; i < 4; ++i)
#pragma unroll
        for (int j = 0; j < 4; ++j) acc[i][j] = fzero;

    for (int k0 = 0; k0 < K; k0 += 32) {
        gl_lds16(A + (size_t)(m0 + w * 32 + srow) * K + k0 + scol,       As + (w * 32) * 32);
        gl_lds16(A + (size_t)(m0 + w * 32 + 16 + srow) * K + k0 + scol,  As + (w * 32 + 16) * 32);
        gl_lds16(Bt + (size_t)(n0 + w * 32 + srow) * K + k0 + scol,      Bs + (w * 32) * 32);
        gl_lds16(Bt + (size_t)(n0 + w * 32 + 16 + srow) * K + k0 + scol, Bs + (w * 32 + 16) * 32);
        __syncthreads();
        bf16x8 a[4], b[4];
#pragma unroll
        for (int i = 0; i < 4; ++i)
            a[i] = *(const bf16x8*)(As + (mw + i * 16 + l16) * 32 + quad * 8);
#pragma unroll
        for (int j = 0; j < 4; ++j)
            b[j] = *(const bf16x8*)(Bs + (nw + j * 16 + l16) * 32 + quad * 8);
#pragma unroll
        for (int i = 0; i < 4; ++i)
#pragma unroll
            for (int j = 0; j < 4; ++j)
                acc[i][j] = __builtin_amdgcn_mfma_f32_16x16x32_bf16(a[i], b[j], acc[i][j], 0, 0, 0);
        __syncthreads();
    }

#pragma unroll
    for (int j = 0; j < 4; ++j) {
        int gn = n0 + nw + j * 16 + l16;
        float bias = bo[gn];
#pragma unroll
        for (int i = 0; i < 4; ++i) {
            int gmb = m0 + mw + i * 16 + quad * 4;
#pragma unroll
            for (int r = 0; r < 4; ++r)
                out[(size_t)(gmb + r) * 1024 + gn] = acc[i][j][r] + bias;
        }
    }
}

extern "C" void kernel_launch(void* const* d_in, const int* in_sizes, int n_in,
                              void* d_out, int out_size, void* d_ws, size_t ws_size,
                              hipStream_t stream) {
    const float* hs  = (const float*)d_in[0];
    const int* mask  = (const int*)d_in[1];
    const float* Wq  = (const float*)d_in[2];
    const float* Wk  = (const float*)d_in[3];
    const float* Wv  = (const float*)d_in[4];
    const float* Wo  = (const float*)d_in[5];
    const float* bo  = (const float*)d_in[6];
    float* out = (float*)d_out;

    char* ws = (char*)d_ws;
    unsigned short* hs_bf = (unsigned short*)(ws);                  // 16 MB
    unsigned short* wqkv  = (unsigned short*)(ws + 16777216);       // 6 MB
    unsigned short* wo_t  = (unsigned short*)(ws + 23068672);       // 2 MB
    unsigned short* Qg    = (unsigned short*)(ws + 25165824);       // 16 MB
    unsigned short* Kf    = (unsigned short*)(ws + 41943040);       // 16 MB
    unsigned short* Vf    = (unsigned short*)(ws + 58720256);       // 16 MB
    unsigned short* AO    = (unsigned short*)(ws + 75497472);       // 16 MB

    cvt_hs_kernel<<<8192, 256, 0, stream>>>((const float4*)hs, (ushort4*)hs_bf);
    wtrans_kernel<<<dim3(256, 4), 256, 0, stream>>>(Wq, Wk, Wv, Wo, wqkv, wo_t);
    gemm_qkv_kernel<<<dim3(24, 64), 256, 0, stream>>>(hs_bf, wqkv, Qg, Kf, Vf);
    attn_kernel<<<1024, 256, 0, stream>>>(Qg, Kf, Vf, mask, AO);
    gemm_out_kernel<<<dim3(8, 64), 256, 0, stream>>>(AO, wo_t, bo, out);
}